// Round 5
// baseline (288.033 us; speedup 1.0000x reference)
//
#include <hip/hip_runtime.h>
#include <hip/hip_bf16.h>

using bf16 = __hip_bfloat16;
typedef __attribute__((ext_vector_type(4))) float f32x4;
typedef short s16x8 __attribute__((ext_vector_type(8)));
typedef unsigned short u16x8 __attribute__((ext_vector_type(8)));

__device__ __forceinline__ unsigned short f2b(float f) {
  bf16 h = __float2bfloat16(f);
  return __builtin_bit_cast(unsigned short, h);
}
__device__ __forceinline__ float b2f(unsigned short u) {
  bf16 h = __builtin_bit_cast(bf16, u);
  return __bfloat162float(h);
}

__device__ __forceinline__ void async_copy16(const void* g, void* lds) {
  __builtin_amdgcn_global_load_lds(
      (const __attribute__((address_space(1))) void*)g,
      (__attribute__((address_space(3))) void*)lds, 16, 0, 0);
}

// ---------------- fp32 -> bf16 convert (8 elems/thread) ----------------
__global__ __launch_bounds__(256) void cvt_f32_to_bf16(const float* __restrict__ in,
                                                       ushort* __restrict__ out) {
  long i = ((long)blockIdx.x * 256 + threadIdx.x) * 8;
  float4 a = *(const float4*)(in + i);
  float4 b = *(const float4*)(in + i + 4);
  u16x8 o;
  o[0] = f2b(a.x); o[1] = f2b(a.y); o[2] = f2b(a.z); o[3] = f2b(a.w);
  o[4] = f2b(b.x); o[5] = f2b(b.y); o[6] = f2b(b.z); o[7] = f2b(b.w);
  *(u16x8*)(out + i) = o;
}

// ---------------- RoPE in-place on q,k halves; q additionally scaled ------
// q *= 0.125*log2(e) so attention softmax runs in exp2 domain with no muls.
__global__ __launch_bounds__(256) void rope_kernel(ushort* __restrict__ qkv,
                                                   const float* __restrict__ cosT,
                                                   const float* __restrict__ sinT) {
  long idx = (long)blockIdx.x * 256 + threadIdx.x;  // 2,097,152 total
  int d4 = (int)(idx & 7) * 4;
  int h = (int)((idx >> 3) & 15);
  int which = (int)((idx >> 7) & 1);
  long row = idx >> 8;          // 0..8191
  int s = (int)(row & 2047);
  long base = row * 3072 + which * 1024 + h * 64 + d4;
  float sc = which ? 1.0f : 0.18033688011112042f;  // q gets scale*log2e
  ushort4 lo = *(ushort4*)(qkv + base);
  ushort4 hi = *(ushort4*)(qkv + base + 32);
  float4 c0 = *(const float4*)(cosT + s * 64 + d4);
  float4 c1 = *(const float4*)(cosT + s * 64 + d4 + 32);
  float4 s0 = *(const float4*)(sinT + s * 64 + d4);
  float4 s1 = *(const float4*)(sinT + s * 64 + d4 + 32);
  float l0 = b2f(lo.x), l1 = b2f(lo.y), l2 = b2f(lo.z), l3 = b2f(lo.w);
  float h0 = b2f(hi.x), h1 = b2f(hi.y), h2 = b2f(hi.z), h3 = b2f(hi.w);
  ushort4 olo, ohi;
  olo.x = f2b((l0 * c0.x - h0 * s0.x) * sc); ohi.x = f2b((h0 * c1.x + l0 * s1.x) * sc);
  olo.y = f2b((l1 * c0.y - h1 * s0.y) * sc); ohi.y = f2b((h1 * c1.y + l1 * s1.y) * sc);
  olo.z = f2b((l2 * c0.z - h2 * s0.z) * sc); ohi.z = f2b((h2 * c1.z + l2 * s1.z) * sc);
  olo.w = f2b((l3 * c0.w - h3 * s0.w) * sc); ohi.w = f2b((h3 * c1.w + l3 * s1.w) * sc);
  *(ushort4*)(qkv + base) = olo;
  *(ushort4*)(qkv + base + 32) = ohi;
}

// ---------------- V transpose: qkv V-part -> vtg[pair][d][2048] ----------
__global__ __launch_bounds__(256) void transpose_v(const bf16* __restrict__ qkv,
                                                   ushort* __restrict__ vtg) {
  const int pair = blockIdx.y;
  const int b = pair >> 4, h = pair & 15;
  const int st = blockIdx.x * 64;
  const int tid = threadIdx.x;
  __shared__ ushort T[64][68];
  const ushort* src = (const ushort*)qkv + (long)(b * 2048 + st) * 3072 + 2048 + h * 64;
#pragma unroll
  for (int i = 0; i < 4; ++i) {
    int c2 = tid + i * 256;
    int row = c2 >> 4;          // s_local
    int d4 = (c2 & 15) * 4;
    *(ushort4*)&T[row][d4] = *(const ushort4*)(src + (long)row * 3072 + d4);
  }
  __syncthreads();
#pragma unroll
  for (int i = 0; i < 4; ++i) {
    int c2 = tid + i * 256;
    int d = c2 >> 4;
    int s4 = (c2 & 15) * 4;
    ushort4 w;
    w.x = T[s4][d]; w.y = T[s4 + 1][d]; w.z = T[s4 + 2][d]; w.w = T[s4 + 3][d];
    *(ushort4*)(vtg + (long)pair * 131072 + (long)d * 2048 + st + s4) = w;
  }
}

// ---------------- bf16 GEMM: C[M][N] = A[M][K] * B[N][K]^T ----------------
__device__ __forceinline__ void storeC(float* p, float v) { *p = v; }
__device__ __forceinline__ void storeC(bf16* p, float v) { *p = __float2bfloat16(v); }

template <typename CT>
__global__ __launch_bounds__(256) void gemm_bt(const bf16* __restrict__ A,
                                               const bf16* __restrict__ B,
                                               CT* __restrict__ C,
                                               int M, int N, int K) {
  __shared__ bf16 As[128 * 64];
  __shared__ bf16 Bs[128 * 64];
  const int tid = threadIdx.x;
  const int lane = tid & 63;
  const int wid = tid >> 6;
  const int tm = blockIdx.y * 128;
  const int tn = blockIdx.x * 128;
  const int wr = wid >> 1, wc = wid & 1;
  const int srow = tid >> 3;
  const int scol = (tid & 7) * 8;

  f32x4 acc[4][4] = {};

  const bf16* Abase = A + (long)(tm + srow) * K + scol;
  const bf16* Bbase = B + (long)(tn + srow) * K + scol;

  const int lr = lane & 15;
  const int lk = (lane >> 4) * 8;

  for (int k0 = 0; k0 < K; k0 += 64) {
#pragma unroll
    for (int i = 0; i < 4; ++i) {
      async_copy16(Abase + (long)i * 32 * K + k0, (char*)As + wid * 1024 + i * 4096);
      async_copy16(Bbase + (long)i * 32 * K + k0, (char*)Bs + wid * 1024 + i * 4096);
    }
    __syncthreads();
#pragma unroll
    for (int ks = 0; ks < 2; ++ks) {
      s16x8 af[4], bff[4];
#pragma unroll
      for (int m = 0; m < 4; ++m)
        af[m] = *(const s16x8*)&As[(wr * 64 + m * 16 + lr) * 64 + ks * 32 + lk];
#pragma unroll
      for (int n = 0; n < 4; ++n)
        bff[n] = *(const s16x8*)&Bs[(wc * 64 + n * 16 + lr) * 64 + ks * 32 + lk];
#pragma unroll
      for (int m = 0; m < 4; ++m)
#pragma unroll
        for (int n = 0; n < 4; ++n)
          acc[m][n] = __builtin_amdgcn_mfma_f32_16x16x32_bf16(af[m], bff[n], acc[m][n], 0, 0, 0);
    }
    __syncthreads();
  }

  const int cc = lane & 15;
  const int cr = (lane >> 4) * 4;
#pragma unroll
  for (int m = 0; m < 4; ++m)
#pragma unroll
    for (int n = 0; n < 4; ++n) {
      long row0 = tm + wr * 64 + m * 16 + cr;
      long col = tn + wc * 64 + n * 16 + cc;
#pragma unroll
      for (int r = 0; r < 4; ++r)
        storeC(&C[(row0 + r) * (long)N + col], acc[m][n][r]);
    }
}

// ---------------- flash attention, swapped QK^T, 16 q-rows/wave -----------
// 1D grid 2048 blocks, XCD-grouped: all 32 q-blocks of a (b,h) pair run on
// one XCD, consecutive in dispatch order -> K/V served from that XCD's L2.
// LDS 24KB -> 6 blocks/CU; 4 waves x 16 q-rows = 64 q-rows per block.
__global__ __launch_bounds__(256, 6) void attn_kernel(const bf16* __restrict__ qkv,
                                                      const ushort* __restrict__ vtg,
                                                      ushort* __restrict__ o) {
  const int bid = blockIdx.x;
  const int xcd = bid & 7;
  const int w = bid >> 3;
  const int pair = xcd * 8 + (w >> 5);   // 8 pairs per XCD
  const int qtile = w & 31;
  const int b = pair >> 4, h = pair & 15;
  const int q0 = qtile * 64;
  const int tid = threadIdx.x, lane = tid & 63, wid = tid >> 6;

  const bf16* Qb = qkv + (long)b * 2048 * 3072 + h * 64;
  const bf16* Kb = Qb + 1024;
  const ushort* Vg = vtg + (long)pair * 131072;   // [64 d][2048 keys]

  __shared__ bf16 Ks[64 * 64];       // [key][d], 128B rows, XOR-swizzled
  __shared__ bf16 Vs[64 * 64];       // [d][key], 128B rows, XOR-swizzled
  __shared__ ushort Ps[4][16 * 64];  // per-wave [q][key], XOR-swizzled (8KB)

  const int lr = lane & 15;
  const int g = lane >> 4;
  const int lk = g * 8;
  const int sw = (lr & 7) << 4;

  // staging geometry: thread owns 16B of rows srow and srow+32
  const int srow = tid >> 3;              // 0..31
  const int scolb = (tid & 7) * 16;       // byte col in 128B row
  const int kdst = srow * 128 + (scolb ^ ((srow & 7) << 4));
  const ushort* Kg = (const ushort*)Kb + (long)srow * 3072 + (scolb >> 1);
  const ushort* Vgp = Vg + (long)srow * 2048 + (scolb >> 1);

  // Q fragments (B operand of swapped QK^T); q pre-scaled by scale*log2e
  s16x8 qa[2];
#pragma unroll
  for (int ks = 0; ks < 2; ++ks)
    qa[ks] = *(const s16x8*)(Qb + (long)(q0 + wid * 16 + lr) * 3072 + ks * 32 + lk);

  f32x4 oacc[4] = {};                // [dfrag], row=qlocal(g*4+r), col=d(lr)
  float mrow = -1e30f;
  float lrow = 0.f;

  // prologue: stage tile 0 through registers
  {
    int4 k0 = *(const int4*)(Kg);
    int4 k1 = *(const int4*)(Kg + 32 * 3072);
    int4 v0 = *(const int4*)(Vgp);
    int4 v1 = *(const int4*)(Vgp + 32 * 2048);
    *(int4*)((char*)Ks + kdst) = k0;
    *(int4*)((char*)Ks + kdst + 4096) = k1;
    *(int4*)((char*)Vs + kdst) = v0;
    *(int4*)((char*)Vs + kdst + 4096) = v1;
  }
  __syncthreads();

  for (int kt = 0; kt < 32; ++kt) {
    // T14 issue-early: next tile -> regs (latency hides under this tile's compute)
    const long ktn = (kt < 31) ? kt + 1 : 31;
    int4 nk0 = *(const int4*)(Kg + ktn * 64 * 3072);
    int4 nk1 = *(const int4*)(Kg + ktn * 64 * 3072 + 32 * 3072);
    int4 nv0 = *(const int4*)(Vgp + ktn * 64);
    int4 nv1 = *(const int4*)(Vgp + ktn * 64 + 32 * 2048);

    // S^T = K Q^T : sacc[n], row = key_local(g*4+r), col = q_local(lr)
    f32x4 sacc[4] = {};
    __builtin_amdgcn_s_setprio(1);
#pragma unroll
    for (int ks = 0; ks < 2; ++ks) {
      s16x8 kf[4];
#pragma unroll
      for (int n = 0; n < 4; ++n) {
        int row = n * 16 + lr;
        kf[n] = *(const s16x8*)((const char*)Ks + row * 128 + ((ks * 64 + g * 16) ^ sw));
      }
#pragma unroll
      for (int n = 0; n < 4; ++n)
        sacc[n] = __builtin_amdgcn_mfma_f32_16x16x32_bf16(kf[n], qa[ks], sacc[n], 0, 0, 0);
    }
    __builtin_amdgcn_s_setprio(0);

    // ---- softmax (exp2 domain; S already scaled via q) ----
    float a0 = fmaxf(fmaxf(sacc[0][0], sacc[0][1]), fmaxf(sacc[0][2], sacc[0][3]));
    float a1 = fmaxf(fmaxf(sacc[1][0], sacc[1][1]), fmaxf(sacc[1][2], sacc[1][3]));
    float a2 = fmaxf(fmaxf(sacc[2][0], sacc[2][1]), fmaxf(sacc[2][2], sacc[2][3]));
    float a3 = fmaxf(fmaxf(sacc[3][0], sacc[3][1]), fmaxf(sacc[3][2], sacc[3][3]));
    float vmax = fmaxf(fmaxf(a0, a1), fmaxf(a2, a3));
    vmax = fmaxf(vmax, __shfl_xor(vmax, 16, 64));
    vmax = fmaxf(vmax, __shfl_xor(vmax, 32, 64));

    bool need = !__all(vmax <= mrow + 8.f);
    if (need) {
      float mnew = fmaxf(mrow, vmax);
      float al = exp2f(mrow - mnew);
      mrow = mnew;
      lrow *= al;
#pragma unroll
      for (int r = 0; r < 4; ++r) {
        float a = __shfl(al, (g << 2) + r, 64);
#pragma unroll
        for (int n2 = 0; n2 < 4; ++n2) oacc[n2][r] *= a;
      }
    }

    {
      float psn[4];
      char* pbase = (char*)&Ps[wid][0] + lr * 128;
#pragma unroll
      for (int n = 0; n < 4; ++n) {
        float p0 = exp2f(sacc[n][0] - mrow);
        float p1 = exp2f(sacc[n][1] - mrow);
        float p2 = exp2f(sacc[n][2] - mrow);
        float p3 = exp2f(sacc[n][3] - mrow);
        psn[n] = (p0 + p1) + (p2 + p3);
        ushort4 wv;
        wv.x = f2b(p0); wv.y = f2b(p1); wv.z = f2b(p2); wv.w = f2b(p3);
        *(ushort4*)(pbase + ((n * 32 + g * 8) ^ sw)) = wv;
      }
      float ps = (psn[0] + psn[1]) + (psn[2] + psn[3]);
      ps += __shfl_xor(ps, 16, 64);
      ps += __shfl_xor(ps, 32, 64);
      lrow += ps;
    }

    // O += P V : A = P rows (q), B = Vs rows (d)
    __builtin_amdgcn_s_setprio(1);
#pragma unroll
    for (int ks = 0; ks < 2; ++ks) {
      s16x8 pa, vf[4];
      pa = *(const s16x8*)((const char*)&Ps[wid][0] + lr * 128 + ((ks * 64 + g * 16) ^ sw));
#pragma unroll
      for (int n = 0; n < 4; ++n) {
        int row = n * 16 + lr;
        vf[n] = *(const s16x8*)((const char*)Vs + row * 128 + ((ks * 64 + g * 16) ^ sw));
      }
#pragma unroll
      for (int n = 0; n < 4; ++n)
        oacc[n] = __builtin_amdgcn_mfma_f32_16x16x32_bf16(pa, vf[n], oacc[n], 0, 0, 0);
    }
    __builtin_amdgcn_s_setprio(0);

    __syncthreads();                   // all waves done reading Ks/Vs
    if (kt < 31) {
      *(int4*)((char*)Ks + kdst) = nk0;          // write-late: staged regs -> LDS
      *(int4*)((char*)Ks + kdst + 4096) = nk1;
      *(int4*)((char*)Vs + kdst) = nv0;
      *(int4*)((char*)Vs + kdst + 4096) = nv1;
      __syncthreads();                 // new tile visible
    }
  }

  // epilogue: O/l -> o[b*2048+s][h*64+d] (bf16)
#pragma unroll
  for (int r = 0; r < 4; ++r) {
    float inv = 1.f / __shfl(lrow, (g << 2) + r, 64);
    int rl = g * 4 + r;
    long srow2 = q0 + wid * 16 + rl;
#pragma unroll
    for (int n = 0; n < 4; ++n) {
      int d = n * 16 + lr;
      o[((long)b * 2048 + srow2) * 1024 + h * 64 + d] = f2b(oacc[n][r] * inv);
    }
  }
}

// ---------------- launch ----------------
extern "C" void kernel_launch(void* const* d_in, const int* in_sizes, int n_in,
                              void* d_out, int out_size, void* d_ws, size_t ws_size,
                              hipStream_t stream) {
  const float* x    = (const float*)d_in[0];
  const float* cosT = (const float*)d_in[1];
  const float* sinT = (const float*)d_in[2];
  const float* Wqkv = (const float*)d_in[3];
  const float* Wout = (const float*)d_in[4];
  float* out = (float*)d_out;

  char* p = (char*)d_ws;
  bf16* xb    = (bf16*)p; p += (size_t)8192 * 1024 * 2;   // dead after gemm1; reused as vtg
  bf16* wqkvb = (bf16*)p; p += (size_t)3072 * 1024 * 2;
  bf16* woutb = (bf16*)p; p += (size_t)1024 * 1024 * 2;
  bf16* qkvb  = (bf16*)p; p += (size_t)8192 * 3072 * 2;
  bf16* ob    = (bf16*)p;
  ushort* vtg = (ushort*)xb;   // 64*64*2048 ushorts == xb's 16.8 MB exactly

  cvt_f32_to_bf16<<<4096, 256, 0, stream>>>(x, (ushort*)xb);
  cvt_f32_to_bf16<<<1536, 256, 0, stream>>>(Wqkv, (ushort*)wqkvb);
  cvt_f32_to_bf16<<<512, 256, 0, stream>>>(Wout, (ushort*)woutb);

  // qkv = x @ Wqkv^T : M=8192, N=3072, K=1024
  gemm_bt<bf16><<<dim3(24, 64), 256, 0, stream>>>(xb, wqkvb, qkvb, 8192, 3072, 1024);

  rope_kernel<<<8192, 256, 0, stream>>>((ushort*)qkvb, cosT, sinT);

  // vtg[pair][d][s] <- V (x/xb no longer needed)
  transpose_v<<<dim3(32, 64), 256, 0, stream>>>(qkvb, vtg);

  attn_kernel<<<2048, 256, 0, stream>>>(qkvb, vtg, (ushort*)ob);

  // out = o @ Wout^T : M=8192, N=1024, K=1024 (fp32 out)
  gemm_bt<float><<<dim3(8, 64), 256, 0, stream>>>(ob, woutb, out, 8192, 1024, 1024);
}

// Round 6
// 262.239 us; speedup vs baseline: 1.0984x; 1.0984x over previous
//
#include <hip/hip_runtime.h>
#include <hip/hip_bf16.h>

using bf16 = __hip_bfloat16;
typedef __attribute__((ext_vector_type(4))) float f32x4;
typedef short s16x8 __attribute__((ext_vector_type(8)));
typedef unsigned short u16x8 __attribute__((ext_vector_type(8)));

__device__ __forceinline__ unsigned short f2b(float f) {
  bf16 h = __float2bfloat16(f);
  return __builtin_bit_cast(unsigned short, h);
}
__device__ __forceinline__ float b2f(unsigned short u) {
  bf16 h = __builtin_bit_cast(bf16, u);
  return __bfloat162float(h);
}

__device__ __forceinline__ void async_copy16(const void* g, void* lds) {
  __builtin_amdgcn_global_load_lds(
      (const __attribute__((address_space(1))) void*)g,
      (__attribute__((address_space(3))) void*)lds, 16, 0, 0);
}

// ---------------- fp32 -> bf16 convert (8 elems/thread) ----------------
__global__ __launch_bounds__(256) void cvt_f32_to_bf16(const float* __restrict__ in,
                                                       ushort* __restrict__ out) {
  long i = ((long)blockIdx.x * 256 + threadIdx.x) * 8;
  float4 a = *(const float4*)(in + i);
  float4 b = *(const float4*)(in + i + 4);
  u16x8 o;
  o[0] = f2b(a.x); o[1] = f2b(a.y); o[2] = f2b(a.z); o[3] = f2b(a.w);
  o[4] = f2b(b.x); o[5] = f2b(b.y); o[6] = f2b(b.z); o[7] = f2b(b.w);
  *(u16x8*)(out + i) = o;
}

// ---------------- RoPE in-place on q,k halves; q additionally scaled ------
// q *= 0.125*log2(e) so attention softmax runs in exp2 domain with no muls.
__global__ __launch_bounds__(256) void rope_kernel(ushort* __restrict__ qkv,
                                                   const float* __restrict__ cosT,
                                                   const float* __restrict__ sinT) {
  long idx = (long)blockIdx.x * 256 + threadIdx.x;  // 2,097,152 total
  int d4 = (int)(idx & 7) * 4;
  int h = (int)((idx >> 3) & 15);
  int which = (int)((idx >> 7) & 1);
  long row = idx >> 8;          // 0..8191
  int s = (int)(row & 2047);
  long base = row * 3072 + which * 1024 + h * 64 + d4;
  float sc = which ? 1.0f : 0.18033688011112042f;  // q gets scale*log2e
  ushort4 lo = *(ushort4*)(qkv + base);
  ushort4 hi = *(ushort4*)(qkv + base + 32);
  float4 c0 = *(const float4*)(cosT + s * 64 + d4);
  float4 c1 = *(const float4*)(cosT + s * 64 + d4 + 32);
  float4 s0 = *(const float4*)(sinT + s * 64 + d4);
  float4 s1 = *(const float4*)(sinT + s * 64 + d4 + 32);
  float l0 = b2f(lo.x), l1 = b2f(lo.y), l2 = b2f(lo.z), l3 = b2f(lo.w);
  float h0 = b2f(hi.x), h1 = b2f(hi.y), h2 = b2f(hi.z), h3 = b2f(hi.w);
  ushort4 olo, ohi;
  olo.x = f2b((l0 * c0.x - h0 * s0.x) * sc); ohi.x = f2b((h0 * c1.x + l0 * s1.x) * sc);
  olo.y = f2b((l1 * c0.y - h1 * s0.y) * sc); ohi.y = f2b((h1 * c1.y + l1 * s1.y) * sc);
  olo.z = f2b((l2 * c0.z - h2 * s0.z) * sc); ohi.z = f2b((h2 * c1.z + l2 * s1.z) * sc);
  olo.w = f2b((l3 * c0.w - h3 * s0.w) * sc); ohi.w = f2b((h3 * c1.w + l3 * s1.w) * sc);
  *(ushort4*)(qkv + base) = olo;
  *(ushort4*)(qkv + base + 32) = ohi;
}

// ---------------- V transpose: qkv V-part -> vtg[pair][d][2048] ----------
__global__ __launch_bounds__(256) void transpose_v(const bf16* __restrict__ qkv,
                                                   ushort* __restrict__ vtg) {
  const int pair = blockIdx.y;
  const int b = pair >> 4, h = pair & 15;
  const int st = blockIdx.x * 64;
  const int tid = threadIdx.x;
  __shared__ ushort T[64][68];
  const ushort* src = (const ushort*)qkv + (long)(b * 2048 + st) * 3072 + 2048 + h * 64;
#pragma unroll
  for (int i = 0; i < 4; ++i) {
    int c2 = tid + i * 256;
    int row = c2 >> 4;          // s_local
    int d4 = (c2 & 15) * 4;
    *(ushort4*)&T[row][d4] = *(const ushort4*)(src + (long)row * 3072 + d4);
  }
  __syncthreads();
#pragma unroll
  for (int i = 0; i < 4; ++i) {
    int c2 = tid + i * 256;
    int d = c2 >> 4;
    int s4 = (c2 & 15) * 4;
    ushort4 w;
    w.x = T[s4][d]; w.y = T[s4 + 1][d]; w.z = T[s4 + 2][d]; w.w = T[s4 + 3][d];
    *(ushort4*)(vtg + (long)pair * 131072 + (long)d * 2048 + st + s4) = w;
  }
}

// ---------------- bf16 GEMM: C[M][N] = A[M][K] * B[N][K]^T ----------------
__device__ __forceinline__ void storeC(float* p, float v) { *p = v; }
__device__ __forceinline__ void storeC(bf16* p, float v) { *p = __float2bfloat16(v); }

template <typename CT>
__global__ __launch_bounds__(256) void gemm_bt(const bf16* __restrict__ A,
                                               const bf16* __restrict__ B,
                                               CT* __restrict__ C,
                                               int M, int N, int K) {
  __shared__ bf16 As[128 * 64];
  __shared__ bf16 Bs[128 * 64];
  const int tid = threadIdx.x;
  const int lane = tid & 63;
  const int wid = tid >> 6;
  const int tm = blockIdx.y * 128;
  const int tn = blockIdx.x * 128;
  const int wr = wid >> 1, wc = wid & 1;
  const int srow = tid >> 3;
  const int scol = (tid & 7) * 8;

  f32x4 acc[4][4] = {};

  const bf16* Abase = A + (long)(tm + srow) * K + scol;
  const bf16* Bbase = B + (long)(tn + srow) * K + scol;

  const int lr = lane & 15;
  const int lk = (lane >> 4) * 8;

  for (int k0 = 0; k0 < K; k0 += 64) {
#pragma unroll
    for (int i = 0; i < 4; ++i) {
      async_copy16(Abase + (long)i * 32 * K + k0, (char*)As + wid * 1024 + i * 4096);
      async_copy16(Bbase + (long)i * 32 * K + k0, (char*)Bs + wid * 1024 + i * 4096);
    }
    __syncthreads();
#pragma unroll
    for (int ks = 0; ks < 2; ++ks) {
      s16x8 af[4], bff[4];
#pragma unroll
      for (int m = 0; m < 4; ++m)
        af[m] = *(const s16x8*)&As[(wr * 64 + m * 16 + lr) * 64 + ks * 32 + lk];
#pragma unroll
      for (int n = 0; n < 4; ++n)
        bff[n] = *(const s16x8*)&Bs[(wc * 64 + n * 16 + lr) * 64 + ks * 32 + lk];
#pragma unroll
      for (int m = 0; m < 4; ++m)
#pragma unroll
        for (int n = 0; n < 4; ++n)
          acc[m][n] = __builtin_amdgcn_mfma_f32_16x16x32_bf16(af[m], bff[n], acc[m][n], 0, 0, 0);
    }
    __syncthreads();
  }

  const int cc = lane & 15;
  const int cr = (lane >> 4) * 4;
#pragma unroll
  for (int m = 0; m < 4; ++m)
#pragma unroll
    for (int n = 0; n < 4; ++n) {
      long row0 = tm + wr * 64 + m * 16 + cr;
      long col = tn + wc * 64 + n * 16 + cc;
#pragma unroll
      for (int r = 0; r < 4; ++r)
        storeC(&C[(row0 + r) * (long)N + col], acc[m][n][r]);
    }
}

// ---------------- flash attention, swapped QK^T, 32 q-rows/wave -----------
// 1D grid 1024 blocks, XCD-grouped: all 16 q-tiles of a (b,h) pair run on
// one XCD, consecutive in dispatch order -> K/V served from that XCD's L2.
// LDS 32KB -> 4 blocks/CU; 4 waves x 32 q-rows = 128 q-rows per block.
__global__ __launch_bounds__(256, 4) void attn_kernel(const bf16* __restrict__ qkv,
                                                      const ushort* __restrict__ vtg,
                                                      ushort* __restrict__ o) {
  const int bid = blockIdx.x;
  const int xcd = bid & 7;
  const int w = bid >> 3;                // 0..127
  const int pair = xcd * 8 + (w >> 4);   // 8 pairs per XCD
  const int qtile = w & 15;
  const int b = pair >> 4, h = pair & 15;
  const int q0 = qtile * 128;
  const int tid = threadIdx.x, lane = tid & 63, wid = tid >> 6;

  const bf16* Qb = qkv + (long)b * 2048 * 3072 + h * 64;
  const bf16* Kb = Qb + 1024;
  const ushort* Vg = vtg + (long)pair * 131072;   // [64 d][2048 keys]

  __shared__ bf16 Ks[64 * 64];       // [key][d], 128B rows, XOR-swizzled
  __shared__ bf16 Vs[64 * 64];       // [d][key], 128B rows, XOR-swizzled
  __shared__ ushort Ps[4][32 * 64];  // per-wave [q][key], XOR-swizzled

  const int lr = lane & 15;
  const int g = lane >> 4;
  const int lk = g * 8;
  const int sw = (lr & 7) << 4;

  // staging geometry: thread owns 16B of rows srow and srow+32
  const int srow = tid >> 3;              // 0..31
  const int scolb = (tid & 7) * 16;       // byte col in 128B row
  const int kdst = srow * 128 + (scolb ^ ((srow & 7) << 4));
  const ushort* Kg = (const ushort*)Kb + (long)srow * 3072 + (scolb >> 1);
  const ushort* Vgp = Vg + (long)srow * 2048 + (scolb >> 1);

  // Q fragments (B operand of swapped QK^T); q pre-scaled by scale*log2e
  s16x8 qa[2][2];
#pragma unroll
  for (int m = 0; m < 2; ++m)
#pragma unroll
    for (int ks = 0; ks < 2; ++ks)
      qa[m][ks] = *(const s16x8*)(Qb + (long)(q0 + wid * 32 + m * 16 + lr) * 3072 + ks * 32 + lk);

  f32x4 oacc[2][4] = {};
  float mrow[2] = {-1e30f, -1e30f};
  float lrow[2] = {0.f, 0.f};

  // prologue: stage tile 0 through registers
  {
    int4 k0 = *(const int4*)(Kg);
    int4 k1 = *(const int4*)(Kg + 32 * 3072);
    int4 v0 = *(const int4*)(Vgp);
    int4 v1 = *(const int4*)(Vgp + 32 * 2048);
    *(int4*)((char*)Ks + kdst) = k0;
    *(int4*)((char*)Ks + kdst + 4096) = k1;
    *(int4*)((char*)Vs + kdst) = v0;
    *(int4*)((char*)Vs + kdst + 4096) = v1;
  }
  __syncthreads();

  for (int kt = 0; kt < 32; ++kt) {
    // T14 issue-early: next tile -> regs (latency hides under this tile's compute)
    const long ktn = (kt < 31) ? kt + 1 : 31;
    int4 nk0 = *(const int4*)(Kg + ktn * 64 * 3072);
    int4 nk1 = *(const int4*)(Kg + ktn * 64 * 3072 + 32 * 3072);
    int4 nv0 = *(const int4*)(Vgp + ktn * 64);
    int4 nv1 = *(const int4*)(Vgp + ktn * 64 + 32 * 2048);

    // S^T = K Q^T : sacc[n][m], row = key_local(g*4+r), col = q_local(lr)
    f32x4 sacc[4][2] = {};
    __builtin_amdgcn_s_setprio(1);
#pragma unroll
    for (int ks = 0; ks < 2; ++ks) {
      s16x8 kf[4];
#pragma unroll
      for (int n = 0; n < 4; ++n) {
        int row = n * 16 + lr;
        kf[n] = *(const s16x8*)((const char*)Ks + row * 128 + ((ks * 64 + g * 16) ^ sw));
      }
#pragma unroll
      for (int n = 0; n < 4; ++n)
#pragma unroll
        for (int m = 0; m < 2; ++m)
          sacc[n][m] = __builtin_amdgcn_mfma_f32_16x16x32_bf16(kf[n], qa[m][ks], sacc[n][m], 0, 0, 0);
    }
    __builtin_amdgcn_s_setprio(0);

    // ---- softmax (exp2 domain; S already scaled via q) ----
    float vmax[2];
#pragma unroll
    for (int m = 0; m < 2; ++m) {
      float a0 = fmaxf(fmaxf(sacc[0][m][0], sacc[0][m][1]), fmaxf(sacc[0][m][2], sacc[0][m][3]));
      float a1 = fmaxf(fmaxf(sacc[1][m][0], sacc[1][m][1]), fmaxf(sacc[1][m][2], sacc[1][m][3]));
      float a2 = fmaxf(fmaxf(sacc[2][m][0], sacc[2][m][1]), fmaxf(sacc[2][m][2], sacc[2][m][3]));
      float a3 = fmaxf(fmaxf(sacc[3][m][0], sacc[3][m][1]), fmaxf(sacc[3][m][2], sacc[3][m][3]));
      float t = fmaxf(fmaxf(a0, a1), fmaxf(a2, a3));
      t = fmaxf(t, __shfl_xor(t, 16, 64));
      t = fmaxf(t, __shfl_xor(t, 32, 64));
      vmax[m] = t;
    }
    bool need = !__all((vmax[0] <= mrow[0] + 8.f) && (vmax[1] <= mrow[1] + 8.f));
    if (need) {
#pragma unroll
      for (int m = 0; m < 2; ++m) {
        float mnew = fmaxf(mrow[m], vmax[m]);
        float al = exp2f(mrow[m] - mnew);
        mrow[m] = mnew;
        lrow[m] *= al;
#pragma unroll
        for (int r = 0; r < 4; ++r) {
          float a = __shfl(al, (g << 2) + r, 64);
#pragma unroll
          for (int n2 = 0; n2 < 4; ++n2) oacc[m][n2][r] *= a;
        }
      }
    }
#pragma unroll
    for (int m = 0; m < 2; ++m) {
      float psn[4];
      char* pbase = (char*)&Ps[wid][0] + (m * 16 + lr) * 128;
#pragma unroll
      for (int n = 0; n < 4; ++n) {
        float p0 = exp2f(sacc[n][m][0] - mrow[m]);
        float p1 = exp2f(sacc[n][m][1] - mrow[m]);
        float p2 = exp2f(sacc[n][m][2] - mrow[m]);
        float p3 = exp2f(sacc[n][m][3] - mrow[m]);
        psn[n] = (p0 + p1) + (p2 + p3);
        ushort4 wv;
        wv.x = f2b(p0); wv.y = f2b(p1); wv.z = f2b(p2); wv.w = f2b(p3);
        *(ushort4*)(pbase + ((n * 32 + g * 8) ^ sw)) = wv;
      }
      float ps = (psn[0] + psn[1]) + (psn[2] + psn[3]);
      ps += __shfl_xor(ps, 16, 64);
      ps += __shfl_xor(ps, 32, 64);
      lrow[m] += ps;
    }

    // O += P V : A = P rows (q), B = Vs rows (d)
    __builtin_amdgcn_s_setprio(1);
#pragma unroll
    for (int ks = 0; ks < 2; ++ks) {
      s16x8 pa[2], vf[4];
#pragma unroll
      for (int m = 0; m < 2; ++m)
        pa[m] = *(const s16x8*)((const char*)&Ps[wid][0] + (m * 16 + lr) * 128 +
                                ((ks * 64 + g * 16) ^ sw));
#pragma unroll
      for (int n = 0; n < 4; ++n) {
        int row = n * 16 + lr;
        vf[n] = *(const s16x8*)((const char*)Vs + row * 128 + ((ks * 64 + g * 16) ^ sw));
      }
#pragma unroll
      for (int m = 0; m < 2; ++m)
#pragma unroll
        for (int n = 0; n < 4; ++n)
          oacc[m][n] = __builtin_amdgcn_mfma_f32_16x16x32_bf16(pa[m], vf[n], oacc[m][n], 0, 0, 0);
    }
    __builtin_amdgcn_s_setprio(0);

    __syncthreads();                   // all waves done reading Ks/Vs
    if (kt < 31) {
      *(int4*)((char*)Ks + kdst) = nk0;          // write-late: staged regs -> LDS
      *(int4*)((char*)Ks + kdst + 4096) = nk1;
      *(int4*)((char*)Vs + kdst) = nv0;
      *(int4*)((char*)Vs + kdst + 4096) = nv1;
      __syncthreads();                 // new tile visible
    }
  }

  // epilogue: O/l -> o[b*2048+s][h*64+d] (bf16)
#pragma unroll
  for (int m = 0; m < 2; ++m)
#pragma unroll
    for (int r = 0; r < 4; ++r) {
      float inv = 1.f / __shfl(lrow[m], (g << 2) + r, 64);
      int rl = g * 4 + r;
      long srow2 = q0 + wid * 32 + m * 16 + rl;
#pragma unroll
      for (int n = 0; n < 4; ++n) {
        int d = n * 16 + lr;
        o[((long)b * 2048 + srow2) * 1024 + h * 64 + d] = f2b(oacc[m][n][r] * inv);
      }
    }
}

// ---------------- launch ----------------
extern "C" void kernel_launch(void* const* d_in, const int* in_sizes, int n_in,
                              void* d_out, int out_size, void* d_ws, size_t ws_size,
                              hipStream_t stream) {
  const float* x    = (const float*)d_in[0];
  const float* cosT = (const float*)d_in[1];
  const float* sinT = (const float*)d_in[2];
  const float* Wqkv = (const float*)d_in[3];
  const float* Wout = (const float*)d_in[4];
  float* out = (float*)d_out;

  char* p = (char*)d_ws;
  bf16* xb    = (bf16*)p; p += (size_t)8192 * 1024 * 2;   // dead after gemm1; reused as vtg
  bf16* wqkvb = (bf16*)p; p += (size_t)3072 * 1024 * 2;
  bf16* woutb = (bf16*)p; p += (size_t)1024 * 1024 * 2;
  bf16* qkvb  = (bf16*)p; p += (size_t)8192 * 3072 * 2;
  bf16* ob    = (bf16*)p;
  ushort* vtg = (ushort*)xb;   // 64*64*2048 ushorts == xb's 16.8 MB exactly

  cvt_f32_to_bf16<<<4096, 256, 0, stream>>>(x, (ushort*)xb);
  cvt_f32_to_bf16<<<1536, 256, 0, stream>>>(Wqkv, (ushort*)wqkvb);
  cvt_f32_to_bf16<<<512, 256, 0, stream>>>(Wout, (ushort*)woutb);

  // qkv = x @ Wqkv^T : M=8192, N=3072, K=1024
  gemm_bt<bf16><<<dim3(24, 64), 256, 0, stream>>>(xb, wqkvb, qkvb, 8192, 3072, 1024);

  rope_kernel<<<8192, 256, 0, stream>>>((ushort*)qkvb, cosT, sinT);

  // vtg[pair][d][s] <- V (x/xb no longer needed)
  transpose_v<<<dim3(32, 64), 256, 0, stream>>>(qkvb, vtg);

  attn_kernel<<<1024, 256, 0, stream>>>(qkvb, vtg, (ushort*)ob);

  // out = o @ Wout^T : M=8192, N=1024, K=1024 (fp32 out)
  gemm_bt<float><<<dim3(8, 64), 256, 0, stream>>>(ob, woutb, out, 8192, 1024, 1024);
}

// Round 7
// 256.350 us; speedup vs baseline: 1.1236x; 1.0230x over previous
//
#include <hip/hip_runtime.h>
#include <hip/hip_bf16.h>

using bf16 = __hip_bfloat16;
typedef __attribute__((ext_vector_type(4))) float f32x4;
typedef short s16x8 __attribute__((ext_vector_type(8)));
typedef unsigned short u16x8 __attribute__((ext_vector_type(8)));

__device__ __forceinline__ unsigned short f2b(float f) {
  bf16 h = __float2bfloat16(f);
  return __builtin_bit_cast(unsigned short, h);
}
__device__ __forceinline__ float b2f(unsigned short u) {
  bf16 h = __builtin_bit_cast(bf16, u);
  return __bfloat162float(h);
}
// HW packed fp32->bf16 (RNE), 1 instr for 2 values (T12)
__device__ __forceinline__ unsigned cvt_pk_bf16(float lo, float hi) {
  unsigned r;
  asm("v_cvt_pk_bf16_f32 %0, %1, %2" : "=v"(r) : "v"(lo), "v"(hi));
  return r;
}

__device__ __forceinline__ void async_copy16(const void* g, void* lds) {
  __builtin_amdgcn_global_load_lds(
      (const __attribute__((address_space(1))) void*)g,
      (__attribute__((address_space(3))) void*)lds, 16, 0, 0);
}

// ---------------- fp32 -> bf16 convert (8 elems/thread) ----------------
__global__ __launch_bounds__(256) void cvt_f32_to_bf16(const float* __restrict__ in,
                                                       ushort* __restrict__ out) {
  long i = ((long)blockIdx.x * 256 + threadIdx.x) * 8;
  float4 a = *(const float4*)(in + i);
  float4 b = *(const float4*)(in + i + 4);
  u16x8 o;
  o[0] = f2b(a.x); o[1] = f2b(a.y); o[2] = f2b(a.z); o[3] = f2b(a.w);
  o[4] = f2b(b.x); o[5] = f2b(b.y); o[6] = f2b(b.z); o[7] = f2b(b.w);
  *(u16x8*)(out + i) = o;
}

// ---------------- V transpose: qkv V-part -> vtg[pair][d][2048] ----------
__global__ __launch_bounds__(256) void transpose_v(const bf16* __restrict__ qkv,
                                                   ushort* __restrict__ vtg) {
  const int pair = blockIdx.y;
  const int b = pair >> 4, h = pair & 15;
  const int st = blockIdx.x * 64;
  const int tid = threadIdx.x;
  __shared__ ushort T[64][68];
  const ushort* src = (const ushort*)qkv + (long)(b * 2048 + st) * 3072 + 2048 + h * 64;
#pragma unroll
  for (int i = 0; i < 4; ++i) {
    int c2 = tid + i * 256;
    int row = c2 >> 4;          // s_local
    int d4 = (c2 & 15) * 4;
    *(ushort4*)&T[row][d4] = *(const ushort4*)(src + (long)row * 3072 + d4);
  }
  __syncthreads();
#pragma unroll
  for (int i = 0; i < 4; ++i) {
    int c2 = tid + i * 256;
    int d = c2 >> 4;
    int s4 = (c2 & 15) * 4;
    ushort4 w;
    w.x = T[s4][d]; w.y = T[s4 + 1][d]; w.z = T[s4 + 2][d]; w.w = T[s4 + 3][d];
    *(ushort4*)(vtg + (long)pair * 131072 + (long)d * 2048 + st + s4) = w;
  }
}

// ---------------- bf16 GEMM: C[M][N] = A[M][K] * B[N][K]^T ----------------
// ROPE=true (qkv projection): q/k column tiles get RoPE applied in-register
// on the fp32 accumulator; q additionally scaled by 0.125*log2e.
__device__ __forceinline__ void storeC(float* p, float v) { *p = v; }
__device__ __forceinline__ void storeC(bf16* p, float v) { *p = __float2bfloat16(v); }

template <typename CT, bool ROPE>
__global__ __launch_bounds__(256) void gemm_bt(const bf16* __restrict__ A,
                                               const bf16* __restrict__ B,
                                               CT* __restrict__ C,
                                               int M, int N, int K,
                                               const float* __restrict__ cosT,
                                               const float* __restrict__ sinT) {
  __shared__ bf16 As[128 * 64];
  __shared__ bf16 Bs[128 * 64];
  const int tid = threadIdx.x;
  const int lane = tid & 63;
  const int wid = tid >> 6;
  const int tm = blockIdx.y * 128;
  const int tn = blockIdx.x * 128;
  const int wr = wid >> 1, wc = wid & 1;
  const int srow = tid >> 3;
  const int scol = (tid & 7) * 8;

  f32x4 acc[4][4] = {};

  const bf16* Abase = A + (long)(tm + srow) * K + scol;
  const bf16* Bbase = B + (long)(tn + srow) * K + scol;

  const int lr = lane & 15;
  const int lk = (lane >> 4) * 8;

  for (int k0 = 0; k0 < K; k0 += 64) {
#pragma unroll
    for (int i = 0; i < 4; ++i) {
      async_copy16(Abase + (long)i * 32 * K + k0, (char*)As + wid * 1024 + i * 4096);
      async_copy16(Bbase + (long)i * 32 * K + k0, (char*)Bs + wid * 1024 + i * 4096);
    }
    __syncthreads();
#pragma unroll
    for (int ks = 0; ks < 2; ++ks) {
      s16x8 af[4], bff[4];
#pragma unroll
      for (int m = 0; m < 4; ++m)
        af[m] = *(const s16x8*)&As[(wr * 64 + m * 16 + lr) * 64 + ks * 32 + lk];
#pragma unroll
      for (int n = 0; n < 4; ++n)
        bff[n] = *(const s16x8*)&Bs[(wc * 64 + n * 16 + lr) * 64 + ks * 32 + lk];
#pragma unroll
      for (int m = 0; m < 4; ++m)
#pragma unroll
        for (int n = 0; n < 4; ++n)
          acc[m][n] = __builtin_amdgcn_mfma_f32_16x16x32_bf16(af[m], bff[n], acc[m][n], 0, 0, 0);
    }
    __syncthreads();
  }

  const int cc = lane & 15;
  const int cr = (lane >> 4) * 4;
  const int wcol = tn + wc * 64;      // wave's 64-col span (one full head)

  if (ROPE && wcol < 2048) {
    // q or k head: rope pairs (d, d+32) live in frags (n, n+2) of the same lane
    const float sc = (wcol < 1024) ? 0.18033688011112042f : 1.0f;
#pragma unroll
    for (int m = 0; m < 4; ++m)
#pragma unroll
      for (int n = 0; n < 2; ++n) {
        long row0 = tm + wr * 64 + m * 16 + cr;
        long col = wcol + n * 16 + cc;
        int d = n * 16 + cc;
#pragma unroll
        for (int r = 0; r < 4; ++r) {
          int s = (int)((row0 + r) & 2047);
          float lo = acc[m][n][r], hi = acc[m][n + 2][r];
          float c0 = cosT[s * 64 + d], s0v = sinT[s * 64 + d];
          float c1 = cosT[s * 64 + d + 32], s1v = sinT[s * 64 + d + 32];
          storeC(&C[(row0 + r) * (long)N + col], (lo * c0 - hi * s0v) * sc);
          storeC(&C[(row0 + r) * (long)N + col + 32], (hi * c1 + lo * s1v) * sc);
        }
      }
  } else {
#pragma unroll
    for (int m = 0; m < 4; ++m)
#pragma unroll
      for (int n = 0; n < 4; ++n) {
        long row0 = tm + wr * 64 + m * 16 + cr;
        long col = wcol + n * 16 + cc;
#pragma unroll
        for (int r = 0; r < 4; ++r)
          storeC(&C[(row0 + r) * (long)N + col], acc[m][n][r]);
      }
  }
}

// ---------------- flash attention, swapped QK^T, 32 q-rows/wave -----------
// 1D grid 1024 blocks, XCD-grouped: all 16 q-tiles of a (b,h) pair run on
// one XCD -> K/V served from that XCD's L2.  LDS 32KB -> 4 blocks/CU.
__global__ __launch_bounds__(256, 4) void attn_kernel(const bf16* __restrict__ qkv,
                                                      const ushort* __restrict__ vtg,
                                                      ushort* __restrict__ o) {
  const int bid = blockIdx.x;
  const int xcd = bid & 7;
  const int w = bid >> 3;                // 0..127
  const int pair = xcd * 8 + (w >> 4);   // 8 pairs per XCD
  const int qtile = w & 15;
  const int b = pair >> 4, h = pair & 15;
  const int q0 = qtile * 128;
  const int tid = threadIdx.x, lane = tid & 63, wid = tid >> 6;

  const bf16* Qb = qkv + (long)b * 2048 * 3072 + h * 64;
  const bf16* Kb = Qb + 1024;
  const ushort* Vg = vtg + (long)pair * 131072;   // [64 d][2048 keys]

  __shared__ bf16 Ks[64 * 64];       // [key][d], 128B rows, XOR-swizzled
  __shared__ bf16 Vs[64 * 64];       // [d][key], 128B rows, XOR-swizzled
  __shared__ ushort Ps[4][32 * 64];  // per-wave [q][key], XOR-swizzled

  const int lr = lane & 15;
  const int g = lane >> 4;
  const int lk = g * 8;
  const int sw = (lr & 7) << 4;

  // staging geometry: thread owns 16B of rows srow and srow+32
  const int srow = tid >> 3;              // 0..31
  const int scolb = (tid & 7) * 16;       // byte col in 128B row
  const int kdst = srow * 128 + (scolb ^ ((srow & 7) << 4));
  const ushort* Kg = (const ushort*)Kb + (long)srow * 3072 + (scolb >> 1);
  const ushort* Vgp = Vg + (long)srow * 2048 + (scolb >> 1);

  // Q fragments (B operand of swapped QK^T); q pre-scaled by scale*log2e
  s16x8 qa[2][2];
#pragma unroll
  for (int m = 0; m < 2; ++m)
#pragma unroll
    for (int ks = 0; ks < 2; ++ks)
      qa[m][ks] = *(const s16x8*)(Qb + (long)(q0 + wid * 32 + m * 16 + lr) * 3072 + ks * 32 + lk);

  f32x4 oacc[2][4] = {};
  float mrow[2] = {-1e30f, -1e30f};
  float lrow[2] = {0.f, 0.f};

  // prologue: stage tile 0 through registers
  {
    int4 k0 = *(const int4*)(Kg);
    int4 k1 = *(const int4*)(Kg + 32 * 3072);
    int4 v0 = *(const int4*)(Vgp);
    int4 v1 = *(const int4*)(Vgp + 32 * 2048);
    *(int4*)((char*)Ks + kdst) = k0;
    *(int4*)((char*)Ks + kdst + 4096) = k1;
    *(int4*)((char*)Vs + kdst) = v0;
    *(int4*)((char*)Vs + kdst + 4096) = v1;
  }
  __syncthreads();

  for (int kt = 0; kt < 32; ++kt) {
    // T14 issue-early: next tile -> regs (latency hides under this tile's compute)
    const long ktn = (kt < 31) ? kt + 1 : 31;
    int4 nk0 = *(const int4*)(Kg + ktn * 64 * 3072);
    int4 nk1 = *(const int4*)(Kg + ktn * 64 * 3072 + 32 * 3072);
    int4 nv0 = *(const int4*)(Vgp + ktn * 64);
    int4 nv1 = *(const int4*)(Vgp + ktn * 64 + 32 * 2048);

    // S^T = K Q^T : sacc[n][m], row = key_local(g*4+r), col = q_local(lr)
    f32x4 sacc[4][2] = {};
    __builtin_amdgcn_s_setprio(1);
#pragma unroll
    for (int ks = 0; ks < 2; ++ks) {
      s16x8 kf[4];
#pragma unroll
      for (int n = 0; n < 4; ++n) {
        int row = n * 16 + lr;
        kf[n] = *(const s16x8*)((const char*)Ks + row * 128 + ((ks * 64 + g * 16) ^ sw));
      }
#pragma unroll
      for (int n = 0; n < 4; ++n)
#pragma unroll
        for (int m = 0; m < 2; ++m)
          sacc[n][m] = __builtin_amdgcn_mfma_f32_16x16x32_bf16(kf[n], qa[m][ks], sacc[n][m], 0, 0, 0);
    }
    __builtin_amdgcn_s_setprio(0);

    // ---- softmax (exp2 domain; S already scaled via q) ----
    float vmax[2];
#pragma unroll
    for (int m = 0; m < 2; ++m) {
      float a0 = fmaxf(fmaxf(sacc[0][m][0], sacc[0][m][1]), fmaxf(sacc[0][m][2], sacc[0][m][3]));
      float a1 = fmaxf(fmaxf(sacc[1][m][0], sacc[1][m][1]), fmaxf(sacc[1][m][2], sacc[1][m][3]));
      float a2 = fmaxf(fmaxf(sacc[2][m][0], sacc[2][m][1]), fmaxf(sacc[2][m][2], sacc[2][m][3]));
      float a3 = fmaxf(fmaxf(sacc[3][m][0], sacc[3][m][1]), fmaxf(sacc[3][m][2], sacc[3][m][3]));
      float t = fmaxf(fmaxf(a0, a1), fmaxf(a2, a3));
      t = fmaxf(t, __shfl_xor(t, 16, 64));
      t = fmaxf(t, __shfl_xor(t, 32, 64));
      vmax[m] = t;
    }
    bool need = !__all((vmax[0] <= mrow[0] + 8.f) && (vmax[1] <= mrow[1] + 8.f));
    if (need) {
#pragma unroll
      for (int m = 0; m < 2; ++m) {
        float mnew = fmaxf(mrow[m], vmax[m]);
        float al = exp2f(mrow[m] - mnew);
        mrow[m] = mnew;
        lrow[m] *= al;
#pragma unroll
        for (int r = 0; r < 4; ++r) {
          float a = __shfl(al, (g << 2) + r, 64);
#pragma unroll
          for (int n2 = 0; n2 < 4; ++n2) oacc[m][n2][r] *= a;
        }
      }
    }
#pragma unroll
    for (int m = 0; m < 2; ++m) {
      float psn[4];
      char* pbase = (char*)&Ps[wid][0] + (m * 16 + lr) * 128;
#pragma unroll
      for (int n = 0; n < 4; ++n) {
        float p0 = exp2f(sacc[n][m][0] - mrow[m]);
        float p1 = exp2f(sacc[n][m][1] - mrow[m]);
        float p2 = exp2f(sacc[n][m][2] - mrow[m]);
        float p3 = exp2f(sacc[n][m][3] - mrow[m]);
        psn[n] = (p0 + p1) + (p2 + p3);
        uint2 wv;
        wv.x = cvt_pk_bf16(p0, p1);    // 1 instr packs 2 bf16 (was ~8 instrs)
        wv.y = cvt_pk_bf16(p2, p3);
        *(uint2*)(pbase + ((n * 32 + g * 8) ^ sw)) = wv;
      }
      float ps = (psn[0] + psn[1]) + (psn[2] + psn[3]);
      ps += __shfl_xor(ps, 16, 64);
      ps += __shfl_xor(ps, 32, 64);
      lrow[m] += ps;
    }

    // O += P V : A = P rows (q), B = Vs rows (d)
    __builtin_amdgcn_s_setprio(1);
#pragma unroll
    for (int ks = 0; ks < 2; ++ks) {
      s16x8 pa[2], vf[4];
#pragma unroll
      for (int m = 0; m < 2; ++m)
        pa[m] = *(const s16x8*)((const char*)&Ps[wid][0] + (m * 16 + lr) * 128 +
                                ((ks * 64 + g * 16) ^ sw));
#pragma unroll
      for (int n = 0; n < 4; ++n) {
        int row = n * 16 + lr;
        vf[n] = *(const s16x8*)((const char*)Vs + row * 128 + ((ks * 64 + g * 16) ^ sw));
      }
#pragma unroll
      for (int m = 0; m < 2; ++m)
#pragma unroll
        for (int n = 0; n < 4; ++n)
          oacc[m][n] = __builtin_amdgcn_mfma_f32_16x16x32_bf16(pa[m], vf[n], oacc[m][n], 0, 0, 0);
    }
    __builtin_amdgcn_s_setprio(0);

    __syncthreads();                   // all waves done reading Ks/Vs
    if (kt < 31) {
      *(int4*)((char*)Ks + kdst) = nk0;          // write-late: staged regs -> LDS
      *(int4*)((char*)Ks + kdst + 4096) = nk1;
      *(int4*)((char*)Vs + kdst) = nv0;
      *(int4*)((char*)Vs + kdst + 4096) = nv1;
      __syncthreads();                 // new tile visible
    }
  }

  // epilogue: O/l -> o[b*2048+s][h*64+d] (bf16)
#pragma unroll
  for (int m = 0; m < 2; ++m)
#pragma unroll
    for (int r = 0; r < 4; ++r) {
      float inv = 1.f / __shfl(lrow[m], (g << 2) + r, 64);
      int rl = g * 4 + r;
      long srow2 = q0 + wid * 32 + m * 16 + rl;
#pragma unroll
      for (int n = 0; n < 4; ++n) {
        int d = n * 16 + lr;
        o[((long)b * 2048 + srow2) * 1024 + h * 64 + d] = f2b(oacc[m][n][r] * inv);
      }
    }
}

// ---------------- launch ----------------
extern "C" void kernel_launch(void* const* d_in, const int* in_sizes, int n_in,
                              void* d_out, int out_size, void* d_ws, size_t ws_size,
                              hipStream_t stream) {
  const float* x    = (const float*)d_in[0];
  const float* cosT = (const float*)d_in[1];
  const float* sinT = (const float*)d_in[2];
  const float* Wqkv = (const float*)d_in[3];
  const float* Wout = (const float*)d_in[4];
  float* out = (float*)d_out;

  char* p = (char*)d_ws;
  bf16* xb    = (bf16*)p; p += (size_t)8192 * 1024 * 2;   // dead after gemm1; reused as vtg
  bf16* wqkvb = (bf16*)p; p += (size_t)3072 * 1024 * 2;
  bf16* woutb = (bf16*)p; p += (size_t)1024 * 1024 * 2;
  bf16* qkvb  = (bf16*)p; p += (size_t)8192 * 3072 * 2;
  bf16* ob    = (bf16*)p;
  ushort* vtg = (ushort*)xb;   // 64*64*2048 ushorts == xb's 16.8 MB exactly

  cvt_f32_to_bf16<<<4096, 256, 0, stream>>>(x, (ushort*)xb);
  cvt_f32_to_bf16<<<1536, 256, 0, stream>>>(Wqkv, (ushort*)wqkvb);
  cvt_f32_to_bf16<<<512, 256, 0, stream>>>(Wout, (ushort*)woutb);

  // qkv = x @ Wqkv^T with fused RoPE epilogue : M=8192, N=3072, K=1024
  gemm_bt<bf16, true><<<dim3(24, 64), 256, 0, stream>>>(xb, wqkvb, qkvb, 8192, 3072, 1024,
                                                        cosT, sinT);

  // vtg[pair][d][s] <- V (x/xb no longer needed)
  transpose_v<<<dim3(32, 64), 256, 0, stream>>>(qkvb, vtg);

  attn_kernel<<<1024, 256, 0, stream>>>(qkvb, vtg, (ushort*)ob);

  // out = o @ Wout^T : M=8192, N=1024, K=1024 (fp32 out)
  gemm_bt<float, false><<<dim3(8, 64), 256, 0, stream>>>(ob, woutb, out, 8192, 1024, 1024,
                                                         nullptr, nullptr);
}

// Round 9
// 250.345 us; speedup vs baseline: 1.1505x; 1.0240x over previous
//
#include <hip/hip_runtime.h>
#include <hip/hip_bf16.h>

using bf16 = __hip_bfloat16;
typedef __attribute__((ext_vector_type(4))) float f32x4;
typedef __attribute__((ext_vector_type(16))) float f32x16;
typedef short s16x8 __attribute__((ext_vector_type(8)));
typedef unsigned short u16x8 __attribute__((ext_vector_type(8)));

__device__ __forceinline__ unsigned short f2b(float f) {
  bf16 h = __float2bfloat16(f);
  return __builtin_bit_cast(unsigned short, h);
}
// HW packed fp32->bf16 (RNE), 1 instr for 2 values (T12)
__device__ __forceinline__ unsigned cvt_pk_bf16(float lo, float hi) {
  unsigned r;
  asm volatile("v_cvt_pk_bf16_f32 %0, %1, %2" : "=v"(r) : "v"(lo), "v"(hi));
  return r;
}

__device__ __forceinline__ void async_copy16(const void* g, void* lds) {
  __builtin_amdgcn_global_load_lds(
      (const __attribute__((address_space(1))) void*)g,
      (__attribute__((address_space(3))) void*)lds, 16, 0, 0);
}

// ---------------- fp32 -> bf16 convert (8 elems/thread) ----------------
__global__ __launch_bounds__(256) void cvt_f32_to_bf16(const float* __restrict__ in,
                                                       ushort* __restrict__ out) {
  long i = ((long)blockIdx.x * 256 + threadIdx.x) * 8;
  float4 a = *(const float4*)(in + i);
  float4 b = *(const float4*)(in + i + 4);
  u16x8 o;
  o[0] = f2b(a.x); o[1] = f2b(a.y); o[2] = f2b(a.z); o[3] = f2b(a.w);
  o[4] = f2b(b.x); o[5] = f2b(b.y); o[6] = f2b(b.z); o[7] = f2b(b.w);
  *(u16x8*)(out + i) = o;
}

// ---------------- V transpose: qkv V-part -> vtg[pair][d][2048] ----------
__global__ __launch_bounds__(256) void transpose_v(const bf16* __restrict__ qkv,
                                                   ushort* __restrict__ vtg) {
  const int pair = blockIdx.y;
  const int b = pair >> 4, h = pair & 15;
  const int st = blockIdx.x * 64;
  const int tid = threadIdx.x;
  __shared__ ushort T[64][68];
  const ushort* src = (const ushort*)qkv + (long)(b * 2048 + st) * 3072 + 2048 + h * 64;
#pragma unroll
  for (int i = 0; i < 4; ++i) {
    int c2 = tid + i * 256;
    int row = c2 >> 4;          // s_local
    int d4 = (c2 & 15) * 4;
    *(ushort4*)&T[row][d4] = *(const ushort4*)(src + (long)row * 3072 + d4);
  }
  __syncthreads();
#pragma unroll
  for (int i = 0; i < 4; ++i) {
    int c2 = tid + i * 256;
    int d = c2 >> 4;
    int s4 = (c2 & 15) * 4;
    ushort4 w;
    w.x = T[s4][d]; w.y = T[s4 + 1][d]; w.z = T[s4 + 2][d]; w.w = T[s4 + 3][d];
    *(ushort4*)(vtg + (long)pair * 131072 + (long)d * 2048 + st + s4) = w;
  }
}

// ---------------- bf16 GEMM: C[M][N] = A[M][K] * B[N][K]^T ----------------
// ROPE=true (qkv projection): q/k column tiles get RoPE applied in-register
// on the fp32 accumulator; q additionally scaled by 0.125*log2e.
__device__ __forceinline__ void storeC(float* p, float v) { *p = v; }
__device__ __forceinline__ void storeC(bf16* p, float v) { *p = __float2bfloat16(v); }

template <typename CT, bool ROPE>
__global__ __launch_bounds__(256) void gemm_bt(const bf16* __restrict__ A,
                                               const bf16* __restrict__ B,
                                               CT* __restrict__ C,
                                               int M, int N, int K,
                                               const float* __restrict__ cosT,
                                               const float* __restrict__ sinT) {
  __shared__ bf16 As[128 * 64];
  __shared__ bf16 Bs[128 * 64];
  const int tid = threadIdx.x;
  const int lane = tid & 63;
  const int wid = tid >> 6;
  const int tm = blockIdx.y * 128;
  const int tn = blockIdx.x * 128;
  const int wr = wid >> 1, wc = wid & 1;
  const int srow = tid >> 3;
  const int scol = (tid & 7) * 8;

  f32x4 acc[4][4] = {};

  const bf16* Abase = A + (long)(tm + srow) * K + scol;
  const bf16* Bbase = B + (long)(tn + srow) * K + scol;

  const int lr = lane & 15;
  const int lk = (lane >> 4) * 8;

  for (int k0 = 0; k0 < K; k0 += 64) {
#pragma unroll
    for (int i = 0; i < 4; ++i) {
      async_copy16(Abase + (long)i * 32 * K + k0, (char*)As + wid * 1024 + i * 4096);
      async_copy16(Bbase + (long)i * 32 * K + k0, (char*)Bs + wid * 1024 + i * 4096);
    }
    __syncthreads();
#pragma unroll
    for (int ks = 0; ks < 2; ++ks) {
      s16x8 af[4], bff[4];
#pragma unroll
      for (int m = 0; m < 4; ++m)
        af[m] = *(const s16x8*)&As[(wr * 64 + m * 16 + lr) * 64 + ks * 32 + lk];
#pragma unroll
      for (int n = 0; n < 4; ++n)
        bff[n] = *(const s16x8*)&Bs[(wc * 64 + n * 16 + lr) * 64 + ks * 32 + lk];
#pragma unroll
      for (int m = 0; m < 4; ++m)
#pragma unroll
        for (int n = 0; n < 4; ++n)
          acc[m][n] = __builtin_amdgcn_mfma_f32_16x16x32_bf16(af[m], bff[n], acc[m][n], 0, 0, 0);
    }
    __syncthreads();
  }

  const int cc = lane & 15;
  const int cr = (lane >> 4) * 4;
  const int wcol = tn + wc * 64;      // wave's 64-col span (one full head)

  if (ROPE && wcol < 2048) {
    // q or k head: rope pairs (d, d+32) live in frags (n, n+2) of the same lane
    const float sc = (wcol < 1024) ? 0.18033688011112042f : 1.0f;
#pragma unroll
    for (int m = 0; m < 4; ++m)
#pragma unroll
      for (int n = 0; n < 2; ++n) {
        long row0 = tm + wr * 64 + m * 16 + cr;
        long col = wcol + n * 16 + cc;
        int d = n * 16 + cc;
#pragma unroll
        for (int r = 0; r < 4; ++r) {
          int s = (int)((row0 + r) & 2047);
          float lo = acc[m][n][r], hi = acc[m][n + 2][r];
          float c0 = cosT[s * 64 + d], s0v = sinT[s * 64 + d];
          float c1 = cosT[s * 64 + d + 32], s1v = sinT[s * 64 + d + 32];
          storeC(&C[(row0 + r) * (long)N + col], (lo * c0 - hi * s0v) * sc);
          storeC(&C[(row0 + r) * (long)N + col + 32], (hi * c1 + lo * s1v) * sc);
        }
      }
  } else {
#pragma unroll
    for (int m = 0; m < 4; ++m)
#pragma unroll
      for (int n = 0; n < 4; ++n) {
        long row0 = tm + wr * 64 + m * 16 + cr;
        long col = wcol + n * 16 + cc;
#pragma unroll
        for (int r = 0; r < 4; ++r)
          storeC(&C[(row0 + r) * (long)N + col], acc[m][n][r]);
      }
  }
}

// ---------------- flash attention, 32x32 MFMA, in-register softmax --------
// grid 1024 (XCD-grouped), 4 waves x 32 q-rows; K/V double-buffered via
// global_load_lds (pre-swizzled source); P never touches LDS (T12-style,
// partner-half routing via shfl_xor(32) -- unambiguous semantics).
__global__ __launch_bounds__(256, 4) void attn_kernel(const bf16* __restrict__ qkv,
                                                      const ushort* __restrict__ vtg,
                                                      ushort* __restrict__ o) {
  const int bid = blockIdx.x;
  const int xcd = bid & 7;
  const int w = bid >> 3;                // 0..127
  const int pair = xcd * 8 + (w >> 4);   // 8 pairs per XCD
  const int qtile = w & 15;
  const int b = pair >> 4, h = pair & 15;
  const int q0 = qtile * 128;
  const int tid = threadIdx.x, lane = tid & 63, wid = tid >> 6;

  const bf16* Qb = qkv + (long)b * 2048 * 3072 + h * 64;
  const bf16* Kb = Qb + 1024;
  const ushort* Vg = vtg + (long)pair * 131072;   // [64 d][2048 keys]

  __shared__ bf16 Ks[2][64 * 64];    // [key][d], 128B rows, XOR-swizzled
  __shared__ bf16 Vs[2][64 * 64];    // [d][key], 128B rows, XOR-swizzled

  const int ql = lane & 31;          // q owned by this lane (and d for PV B-op)
  const int hi = lane >> 5;          // k-half selector in A/B fragments
  const int sw = (ql & 7) << 4;      // XOR swizzle for ds_read rows (row&7==ql&7)

  // Q fragments (B operand of swapped QK^T); q pre-scaled by 0.125*log2e
  s16x8 qa[4];
  {
    const bf16* qrow = Qb + (long)(q0 + wid * 32 + ql) * 3072 + hi * 8;
#pragma unroll
    for (int ds = 0; ds < 4; ++ds)
      qa[ds] = *(const s16x8*)(qrow + ds * 16);
  }

  f32x16 oacc[2] = {};               // [dblk]; row(reg)=q, col(lane&31)=d
  float mrow = -1e30f, lrow = 0.f;   // per-lane q = ql (dup in lane, lane+32)

  // stage K tile [64 keys][64 d] + Vt tile [64 d][64 keys], swizzled source
  auto stage = [&](int kt, int bb) {
#pragma unroll
    for (int i = 0; i < 2; ++i) {
      int c = tid + i * 256;
      int row = c >> 3;
      int colb = (c & 7) * 16;
      int scolb = colb ^ ((row & 7) << 4);
      async_copy16(Kb + (long)(kt * 64 + row) * 3072 + (scolb >> 1),
                   (char*)Ks + bb * 8192 + wid * 1024 + i * 4096);
      async_copy16(Vg + (long)row * 2048 + kt * 64 + (scolb >> 1),
                   (char*)Vs + bb * 8192 + wid * 1024 + i * 4096);
    }
  };

  stage(0, 0);
  __syncthreads();

  int cur = 0;
  for (int kt = 0; kt < 32; ++kt) {
    if (kt < 31) stage(kt + 1, cur ^ 1);   // prefetch next tile into other buf

    // ---- S^T = K Q^T : sacc[kb] row=key_local(reg-map), col=q(ql) ----
    f32x16 sacc[2] = {};
    __builtin_amdgcn_s_setprio(1);
#pragma unroll
    for (int kb = 0; kb < 2; ++kb) {
      const char* krow = (const char*)Ks + cur * 8192 + (kb * 32 + ql) * 128;
#pragma unroll
      for (int ds = 0; ds < 4; ++ds) {
        s16x8 kf = *(const s16x8*)(krow + ((ds * 32 + hi * 16) ^ sw));
        sacc[kb] = __builtin_amdgcn_mfma_f32_32x32x16_bf16(kf, qa[ds], sacc[kb], 0, 0, 0);
      }
    }
    __builtin_amdgcn_s_setprio(0);

    // ---- in-register softmax (exp2 domain; S pre-scaled via q) ----
    // lane holds, for q=ql, keys {(r&3)+8*(r>>2)+4*hi} (sacc[0]) and +32 (sacc[1])
    float pv[32];
#pragma unroll
    for (int r = 0; r < 16; ++r) { pv[r] = sacc[0][r]; pv[16 + r] = sacc[1][r]; }
    float t16[16];
#pragma unroll
    for (int i = 0; i < 16; ++i) t16[i] = fmaxf(pv[i], pv[i + 16]);
#pragma unroll
    for (int i = 0; i < 8; ++i) t16[i] = fmaxf(t16[i], t16[i + 8]);
#pragma unroll
    for (int i = 0; i < 4; ++i) t16[i] = fmaxf(t16[i], t16[i + 4]);
    float vmax = fmaxf(fmaxf(t16[0], t16[1]), fmaxf(t16[2], t16[3]));
    vmax = fmaxf(vmax, __shfl_xor(vmax, 32, 64));   // partner lane: other 32 keys

    bool need = !__all(vmax <= mrow + 8.f);         // T13 defer-max
    if (need) {
      float mnew = fmaxf(mrow, vmax);
      float al = exp2f(mrow - mnew);
      mrow = mnew;
      lrow *= al;
#pragma unroll
      for (int r = 0; r < 16; ++r) {
        float a = __shfl(al, (r & 3) + 8 * (r >> 2) + 4 * hi, 64);
        oacc[0][r] *= a;
        oacc[1][r] *= a;
      }
    }

#pragma unroll
    for (int i = 0; i < 32; ++i) pv[i] = exp2f(pv[i] - mrow);
    float s16a[16];
#pragma unroll
    for (int i = 0; i < 16; ++i) s16a[i] = pv[i] + pv[i + 16];
#pragma unroll
    for (int i = 0; i < 8; ++i) s16a[i] += s16a[i + 8];
#pragma unroll
    for (int i = 0; i < 4; ++i) s16a[i] += s16a[i + 4];
    float psum = (s16a[0] + s16a[1]) + (s16a[2] + s16a[3]);
    psum += __shfl_xor(psum, 32, 64);
    lrow += psum;

    // ---- pack P -> PV A-fragments in-register (cvt_pk + shfl_xor routing) --
    // pa[s] word w must hold keys s*16 + hi*8 + {2w,2w+1} for q=ql.
    // own words cover keys {s*16+4*hi+0..3, s*16+8+4*hi+0..3}; partner
    // (lane^32) covers the interleaved 4-blocks. Verified routing:
    //   hi=0: [own0, own1, part0, part1] ; hi=1: [part2, part3, own2, own3]
    s16x8 pa[4];
#pragma unroll
    for (int s = 0; s < 4; ++s) {
      unsigned own0 = cvt_pk_bf16(pv[s * 8 + 0], pv[s * 8 + 1]);
      unsigned own1 = cvt_pk_bf16(pv[s * 8 + 2], pv[s * 8 + 3]);
      unsigned own2 = cvt_pk_bf16(pv[s * 8 + 4], pv[s * 8 + 5]);
      unsigned own3 = cvt_pk_bf16(pv[s * 8 + 6], pv[s * 8 + 7]);
      unsigned p0 = __shfl_xor(own0, 32, 64);
      unsigned p1 = __shfl_xor(own1, 32, 64);
      unsigned p2 = __shfl_xor(own2, 32, 64);
      unsigned p3 = __shfl_xor(own3, 32, 64);
      unsigned w0 = hi ? p2 : own0;
      unsigned w1 = hi ? p3 : own1;
      unsigned w2 = hi ? own2 : p0;
      unsigned w3 = hi ? own3 : p1;
      uint4 u{w0, w1, w2, w3};
      pa[s] = __builtin_bit_cast(s16x8, u);
    }

    // ---- O += P V : A = P (row=q), B = Vt rows (col=d) ----
    __builtin_amdgcn_s_setprio(1);
#pragma unroll
    for (int dblk = 0; dblk < 2; ++dblk) {
      const char* vrow = (const char*)Vs + cur * 8192 + (dblk * 32 + ql) * 128;
#pragma unroll
      for (int s = 0; s < 4; ++s) {
        s16x8 vf = *(const s16x8*)(vrow + ((s * 32 + hi * 16) ^ sw));
        oacc[dblk] = __builtin_amdgcn_mfma_f32_32x32x16_bf16(pa[s], vf, oacc[dblk], 0, 0, 0);
      }
    }
    __builtin_amdgcn_s_setprio(0);

    __syncthreads();                  // drains prefetch + gates buffer reuse
    cur ^= 1;
  }

  // ---- epilogue: O/l -> o[b*2048+s][h*64+d] (bf16) ----
  float linv = 1.f / lrow;
#pragma unroll
  for (int r = 0; r < 16; ++r) {
    int qr = (r & 3) + 8 * (r >> 2) + 4 * hi;
    float inv = __shfl(linv, qr, 64);
    long srow = q0 + wid * 32 + qr;
    ushort* orow = o + ((long)b * 2048 + srow) * 1024 + h * 64 + ql;
    orow[0]  = f2b(oacc[0][r] * inv);
    orow[32] = f2b(oacc[1][r] * inv);
  }
}

// ---------------- launch ----------------
extern "C" void kernel_launch(void* const* d_in, const int* in_sizes, int n_in,
                              void* d_out, int out_size, void* d_ws, size_t ws_size,
                              hipStream_t stream) {
  const float* x    = (const float*)d_in[0];
  const float* cosT = (const float*)d_in[1];
  const float* sinT = (const float*)d_in[2];
  const float* Wqkv = (const float*)d_in[3];
  const float* Wout = (const float*)d_in[4];
  float* out = (float*)d_out;

  char* p = (char*)d_ws;
  bf16* xb    = (bf16*)p; p += (size_t)8192 * 1024 * 2;   // dead after gemm1; reused as vtg
  bf16* wqkvb = (bf16*)p; p += (size_t)3072 * 1024 * 2;
  bf16* woutb = (bf16*)p; p += (size_t)1024 * 1024 * 2;
  bf16* qkvb  = (bf16*)p; p += (size_t)8192 * 3072 * 2;
  bf16* ob    = (bf16*)p;
  ushort* vtg = (ushort*)xb;   // 64*64*2048 ushorts == xb's 16.8 MB exactly

  cvt_f32_to_bf16<<<4096, 256, 0, stream>>>(x, (ushort*)xb);
  cvt_f32_to_bf16<<<1536, 256, 0, stream>>>(Wqkv, (ushort*)wqkvb);
  cvt_f32_to_bf16<<<512, 256, 0, stream>>>(Wout, (ushort*)woutb);

  // qkv = x @ Wqkv^T with fused RoPE epilogue : M=8192, N=3072, K=1024
  gemm_bt<bf16, true><<<dim3(24, 64), 256, 0, stream>>>(xb, wqkvb, qkvb, 8192, 3072, 1024,
                                                        cosT, sinT);

  // vtg[pair][d][s] <- V (x/xb no longer needed)
  transpose_v<<<dim3(32, 64), 256, 0, stream>>>(qkvb, vtg);

  attn_kernel<<<1024, 256, 0, stream>>>(qkvb, vtg, (ushort*)ob);

  // out = o @ Wout^T : M=8192, N=1024, K=1024 (fp32 out)
  gemm_bt<float, false><<<dim3(8, 64), 256, 0, stream>>>(ob, woutb, out, 8192, 1024, 1024,
                                                         nullptr, nullptr);
}